// Round 1
// baseline (86.806 us; speedup 1.0000x reference)
//
#include <hip/hip_runtime.h>

// PhysicalCircleLayer on MI355X — round 3: bounding-box scan.
//
// Only pixels with distance <= r = 2*mlen can contribute. sRow/sCol are
// monotone in the pixel index (W in [1,2] > 0), so the candidate set is a
// rectangle [ilo..ihi] x [jlo..jhi] found from the same conservative r2m
// prefilter the round-2 kernel used per-pixel:
//   rv^2 > r2m  =>  d2 = add_rn(rv^2, cv^2) >= rv^2 > r2m  =>  pixel invalid
// (fp32 add of non-negatives is >= each operand; rounding is monotone).
// Typical box is ~400-600 of 10000 pixels -> ~20x less fetch + VALU.
//
// Exactness (tracks fp32 reference bit-for-bit, rounds 1-2 absmax 0.0):
//  - (pix-b)/W precomputed in LDS with IEEE '/' (100 distinct values/axis).
//  - moving_vector = (t7+cp)-(t0+cp) in that order; _rn ops block fma fusion.
//  - d2 = add_rn(row_term^2, col_term^2); fp32 add commutative, so the
//    order-swap (order0==1) does not change d2; x/y are swapped only for the
//    bin geometry (exact octant sign/compare tests).
//  - Heavy path redoes the exact sqrt(d2) <= r test; prefilter margin
//    1.00002 >> 6e-7 relative (+1e-30 abs for r==0) never skips a valid px.
//  - equ_dis uses __fdividef (bit-matched in earlier rounds).
//  - Per-bin min via LDS atomicMin on uint-encoded floats: all candidate
//    equ_dis are positive (den >= 0.05+1e-8, num > 0), where the uint view
//    of fp32 is order-preserving. Init = encode(1e9).

#define INFV 1.0e9f

__global__ __launch_bounds__(256)
void pcl_kernel(const float* __restrict__ seg_maps,
                const float* __restrict__ paras,
                const float* __restrict__ traj,
                const float* __restrict__ cpos,
                float* __restrict__ out)
{
    const int b   = blockIdx.x;
    const int tid = threadIdx.x;

    __shared__ __align__(16) float sRow[100];    // row-axis term (x if !swp, y if swp)
    __shared__ __align__(16) float sCol[100];    // col-axis term (y if !swp, x if swp)
    __shared__ __align__(16) float sCol2[100];   // mul_rn(col term, col term)
    __shared__ int sILo, sIHi, sJLo, sJHi;
    __shared__ unsigned sMin[8];

    const float* pp = paras + b * 6;
    const float W0 = pp[0], W1 = pp[1];
    const float bb0 = pp[2], bb1 = pp[3];
    const bool  swp = (pp[4] == 1.0f);
    const float cp0 = cpos[b * 2 + 0];
    const float cp1 = cpos[b * 2 + 1];

    // moving_length: _obs = traj + cp in fp32 BEFORE the subtraction.
    const float* tp  = traj + b * 16;
    const float o00 = __fadd_rn(tp[0],  cp0);
    const float o01 = __fadd_rn(tp[1],  cp1);
    const float o70 = __fadd_rn(tp[14], cp0);
    const float o71 = __fadd_rn(tp[15], cp1);
    const float mv0 = __fsub_rn(o70, o00);
    const float mv1 = __fsub_rn(o71, o01);
    const float mlen = sqrtf(__fadd_rn(__fmul_rn(mv0, mv0), __fmul_rn(mv1, mv1)));
    const float r    = __fmul_rn(2.0f, mlen);
    // conservative prefilter radius^2 (margin >> 6e-7 relative, + tiny abs for r==0)
    const float r2m  = __fmul_rn(r, r) * 1.00002f + 1e-30f;

    if (tid == 0) { sILo = 1000; sIHi = -1; sJLo = 1000; sJHi = -1; }
    if (tid < 8)  sMin[tid] = __float_as_uint(INFV);
    __syncthreads();

    if (tid < 100) {
        const float a  = ((float)tid - bb0) / W0;         // IEEE divide, matches ref
        const float rv = __fsub_rn(a, swp ? cp1 : cp0);
        sRow[tid] = rv;
        if (__fmul_rn(rv, rv) <= r2m) {                   // row can contain a valid px
            atomicMin(&sILo, tid);
            atomicMax(&sIHi, tid);
        }
    } else if (tid < 200) {
        const int j = tid - 100;
        const float c  = ((float)j - bb1) / W1;           // IEEE divide, matches ref
        const float cv = __fsub_rn(c, swp ? cp0 : cp1);
        const float cv2 = __fmul_rn(cv, cv);
        sCol[j]  = cv;
        sCol2[j] = cv2;
        if (cv2 <= r2m) {                                 // col can contain a valid px
            atomicMin(&sJLo, j);
            atomicMax(&sJHi, j);
        }
    }
    __syncthreads();

    const int ilo = sILo, ihi = sIHi;
    const int jlo = sJLo, jhi = sJHi;

    if (ihi >= 0 && jhi >= 0) {
        const float* smap = seg_maps + (size_t)b * 10000;
        const int w   = jhi - jlo + 1;                    // 1..100
        const int tot = (ihi - ilo + 1) * w;
        for (int p = tid; p < tot; p += 256) {
            const int pi = (int)((unsigned)p / (unsigned)w);
            const int i  = ilo + pi;
            const int j  = jlo + (p - pi * w);
            const float mapv = smap[i * 100 + j];
            const float rv = sRow[i];
            const float d2 = __fadd_rn(__fmul_rn(rv, rv), sCol2[j]);  // ref's x*x + y*y
            if ((mapv > 0.05f) && (d2 <= r2m)) {
                const float dd = sqrtf(d2);               // exact, as reference
                if (dd <= r) {                            // exact validity test
                    const float colv = sCol[j];
                    const float x = swp ? colv : rv;
                    const float y = swp ? rv : colv;
                    // bin = floor(mod(atan2(x,y), 2pi) / (pi/4)), geometric form.
                    const int bin =
                        (y > 0.0f)
                          ? ((x >= 0.0f) ? ((x < y) ? 0 : 1)
                                         : ((-x > y) ? 6 : 7))
                          : ((y < 0.0f)
                               ? ((x > 0.0f) ? ((x > -y) ? 2 : 3)
                                             : ((x > y) ? 4 : 5))
                               : ((x > 0.0f) ? 2
                                  : ((x < 0.0f) ? 6
                                     : ((__float_as_uint(y) & 0x80000000u) ? 4 : 0))));
                    const float e = __fdividef(__fadd_rn(dd, 1.0e-8f),
                                               __fadd_rn(mapv, 1.0e-8f));
                    // positive fp32 -> uint view is order-preserving
                    atomicMin(&sMin[bin], __float_as_uint(e));
                }
            }
        }
    }
    __syncthreads();

    if (tid < 16) {
        float vel = 0.0f, md = 0.0f, dir = 0.0f;
        if (tid < 8) {
            const float v = __uint_as_float(sMin[tid]);
            if (v < INFV) {
                vel = mlen;
                md  = v;
                dir = __fmul_rn(6.28318530717958647692f,
                                __fmul_rn((float)tid + 0.5f, 0.125f));
            }
        }
        float* po = out + (size_t)b * 48 + tid * 3;
        po[0] = vel; po[1] = md; po[2] = dir;
    }
}

extern "C" void kernel_launch(void* const* d_in, const int* in_sizes, int n_in,
                              void* d_out, int out_size, void* d_ws, size_t ws_size,
                              hipStream_t stream) {
    const float* seg_maps = (const float*)d_in[0];
    const float* paras    = (const float*)d_in[1];   // (B,6): W0 W1 b0 b1 ord0 ord1
    const float* traj     = (const float*)d_in[2];   // (B,8,2)
    const float* cpos     = (const float*)d_in[3];   // (B,1,2)
    float* out            = (float*)d_out;           // (B,16,3) fp32

    const int B = in_sizes[1] / 6;
    pcl_kernel<<<B, 256, 0, stream>>>(seg_maps, paras, traj, cpos, out);
}